// Round 1
// baseline (896.265 us; speedup 1.0000x reference)
//
#include <hip/hip_runtime.h>

// ---------- types ----------
typedef __attribute__((ext_vector_type(8))) short bf16x8;
typedef __attribute__((ext_vector_type(4))) float f32x4;
typedef __attribute__((ext_vector_type(4))) int   i32x4;

#define N_ROWS 3136
#define M_COLS 20000
#define KDIM   1536
#define NCT    157            // ceil(20000/128)
#define NRT    25             // ceil(3136/128)
#define PPR    (NCT*9)        // partial candidates per row = 1413

__device__ inline unsigned short f2bf(float f) {
    unsigned u = __float_as_uint(f);
    u += 0x7FFFu + ((u >> 16) & 1u);   // RNE
    return (unsigned short)(u >> 16);
}

// sorted ascending insert, drop old max; all indices static after unroll (stays in VGPRs)
__device__ inline void t9_insert(float (&t)[9], float v) {
    #pragma unroll
    for (int s = 8; s >= 1; --s)
        t[s] = (v <= t[s-1]) ? t[s-1] : fminf(t[s], v);
    t[0] = fminf(t[0], v);
}

// ---------- f32 -> bf16 conversion (vectorized) ----------
__global__ void cvt_bf16_kernel(const float* __restrict__ src,
                                unsigned short* __restrict__ dst, int n4) {
    int i = blockIdx.x * blockDim.x + threadIdx.x;
    int stride = gridDim.x * blockDim.x;
    for (; i < n4; i += stride) {
        float4 v = ((const float4*)src)[i];
        ushort4 o;
        o.x = f2bf(v.x); o.y = f2bf(v.y); o.z = f2bf(v.z); o.w = f2bf(v.w);
        ((ushort4*)dst)[i] = o;
    }
}

// ---------- row squared norms (one wave per row, f32 inputs) ----------
__global__ void row_norms_kernel(const float* __restrict__ src,
                                 float* __restrict__ dst, int rows) {
    int lane = threadIdx.x & 63;
    int row = blockIdx.x * (blockDim.x >> 6) + (threadIdx.x >> 6);
    if (row >= rows) return;
    const float4* p = (const float4*)(src + (size_t)row * KDIM);
    float s = 0.f;
    #pragma unroll
    for (int i = 0; i < 6; ++i) {              // 384 float4 / 64 lanes
        float4 v = p[lane + i * 64];
        s += v.x*v.x + v.y*v.y + v.z*v.z + v.w*v.w;
    }
    #pragma unroll
    for (int off = 32; off > 0; off >>= 1) s += __shfl_down(s, off);
    if (lane == 0) dst[row] = s;
}

// ---------- fused distance GEMM + per-tile top-9 ----------
// 128x128 tile, K-step 32, 4 waves (2x2), 16x16x32 bf16 MFMA, 4x4 frags/wave.
__global__ __launch_bounds__(256, 2) void dist_topk_kernel(
    const unsigned short* __restrict__ Ag,   // [3136][1536] bf16
    const unsigned short* __restrict__ Bg,   // [20000][1536] bf16
    const float* __restrict__ x2, const float* __restrict__ y2,
    float* __restrict__ partials)
{
    __shared__ __align__(16) unsigned short As[128 * 32];
    __shared__ __align__(16) unsigned short Bs[128 * 32];
    __shared__ float Ds[64 * 133];       // d^2 half-tile, stride 133 (conflict-free column scan)
    __shared__ float T9[3 * 64 * 13];    // quarter-results exchange

    const int tid = threadIdx.x;
    const int ct = blockIdx.x, rt = blockIdx.y;
    const int rowBase = rt * 128, colBase = ct * 128;
    const int wave = tid >> 6, lane = tid & 63;

    // staging addresses: 2 x 16B chunks per thread for each of A,B
    const unsigned short* pa[2];
    const unsigned short* pb[2];
    int ldsoff[2];
    #pragma unroll
    for (int i = 0; i < 2; ++i) {
        int flat = i * 256 + tid;        // 0..511
        int r = flat >> 2;               // tile row 0..127
        int kk = (flat & 3) * 8;         // k offset 0,8,16,24
        int ar = rowBase + r; ar = ar < N_ROWS ? ar : N_ROWS - 1;   // clamp (rows>=3136 unused)
        int bc = colBase + r; bc = bc < M_COLS ? bc : M_COLS - 1;
        pa[i] = Ag + (size_t)ar * KDIM + kk;
        pb[i] = Bg + (size_t)bc * KDIM + kk;
        ldsoff[i] = flat * 8;            // ushort elements
    }

    i32x4 ra[2], rb[2];
    #pragma unroll
    for (int i = 0; i < 2; ++i) { ra[i] = *(const i32x4*)pa[i]; rb[i] = *(const i32x4*)pb[i]; }

    const int l15 = lane & 15;
    const int kb = (lane >> 4) * 8;          // A/B fragment k-base
    const int g4 = (lane >> 4) * 4;          // C fragment row-base
    const int wr = (wave >> 1) * 64;
    const int wc = (wave & 1) * 64;

    f32x4 acc[4][4] = {};

    for (int kt = 0; kt < 48; ++kt) {
        #pragma unroll
        for (int i = 0; i < 2; ++i) {
            *(i32x4*)(As + ldsoff[i]) = ra[i];
            *(i32x4*)(Bs + ldsoff[i]) = rb[i];
        }
        __syncthreads();
        if (kt < 47) {                         // prefetch next K-tile during MFMA phase
            int koff = (kt + 1) * 32;
            #pragma unroll
            for (int i = 0; i < 2; ++i) {
                ra[i] = *(const i32x4*)(pa[i] + koff);
                rb[i] = *(const i32x4*)(pb[i] + koff);
            }
        }
        bf16x8 af[4], bfr[4];
        #pragma unroll
        for (int mi = 0; mi < 4; ++mi)
            af[mi] = *(const bf16x8*)(As + (wr + mi * 16 + l15) * 32 + kb);
        #pragma unroll
        for (int ni = 0; ni < 4; ++ni)
            bfr[ni] = *(const bf16x8*)(Bs + (wc + ni * 16 + l15) * 32 + kb);
        #pragma unroll
        for (int mi = 0; mi < 4; ++mi)
            #pragma unroll
            for (int ni = 0; ni < 4; ++ni)
                acc[mi][ni] = __builtin_amdgcn_mfma_f32_16x16x32_bf16(af[mi], bfr[ni], acc[mi][ni], 0, 0, 0);
        __syncthreads();
    }

    // epilogue: two passes of 64 rows (keeps LDS < 64KB)
    for (int pass = 0; pass < 2; ++pass) {
        if ((wave >> 1) == pass) {
            #pragma unroll
            for (int ni = 0; ni < 4; ++ni) {
                int c = wc + ni * 16 + l15;
                int gc = colBase + c;
                float yv = y2[gc < M_COLS ? gc : M_COLS - 1];
                #pragma unroll
                for (int mi = 0; mi < 4; ++mi) {
                    #pragma unroll
                    for (int j = 0; j < 4; ++j) {
                        int rloc = mi * 16 + g4 + j;          // 0..63
                        int gr = rowBase + pass * 64 + rloc;
                        float xv = x2[gr < N_ROWS ? gr : N_ROWS - 1];
                        Ds[rloc * 133 + c] = xv + yv - 2.0f * acc[mi][ni][j];
                    }
                }
            }
        }
        __syncthreads();
        // 4-way column-split scan: thread (q, r) scans cols [q*32, q*32+32)
        int r = tid & 63, q = tid >> 6;
        int grow = rowBase + pass * 64 + r;
        int ncols = M_COLS - colBase; ncols = ncols < 128 ? ncols : 128;
        float t9[9];
        #pragma unroll
        for (int s = 0; s < 9; ++s) t9[s] = 3.4e38f;
        int cs = q * 32;
        int ce = (cs + 32 < ncols) ? cs + 32 : ncols;
        for (int c = cs; c < ce; ++c) t9_insert(t9, Ds[r * 133 + c]);
        if (q > 0) {
            #pragma unroll
            for (int s = 0; s < 9; ++s) T9[((q - 1) * 64 + r) * 13 + s] = t9[s];
        }
        __syncthreads();
        if (q == 0 && grow < N_ROWS) {
            #pragma unroll
            for (int qq = 0; qq < 3; ++qq)
                #pragma unroll
                for (int s = 0; s < 9; ++s)
                    t9_insert(t9, T9[(qq * 64 + r) * 13 + s]);
            float* dst = partials + (size_t)grow * PPR + ct * 9;
            #pragma unroll
            for (int s = 0; s < 9; ++s) dst[s] = t9[s];
        }
        __syncthreads();
    }
}

// ---------- merge 157 sorted-9 lists per row -> final top-9 (sqrt applied) ----------
__global__ void merge_topk_kernel(const float* __restrict__ partials,
                                  float* __restrict__ scores) {
    int row = blockIdx.x * blockDim.x + threadIdx.x;
    if (row >= N_ROWS) return;
    const float* p = partials + (size_t)row * PPR;
    float t9[9];
    #pragma unroll
    for (int s = 0; s < 9; ++s) t9[s] = 3.4e38f;
    for (int i = 0; i < PPR; ++i) {
        float v = p[i];
        if (v < t9[8]) t9_insert(t9, v);
    }
    #pragma unroll
    for (int s = 0; s < 9; ++s)
        scores[row * 9 + s] = sqrtf(fmaxf(t9[s], 0.f));
}

// ---------- gaussian blur (fused with x8 nearest upsample), sigma=4, K=33 ----------
__global__ void blur_h_kernel(const float* __restrict__ scores, float* __restrict__ tH) {
    int idx = blockIdx.x * blockDim.x + threadIdx.x;
    if (idx >= 4 * 224 * 28) return;
    int pw = idx % 28, y = (idx / 28) % 224, b = idx / (28 * 224);
    float acc = 0.f, gsum = 0.f;
    #pragma unroll
    for (int k = 0; k < 33; ++k) {
        float xk = (float)(k - 16);
        float w = expf(-xk * xk * (1.0f / 32.0f));
        gsum += w;
        int yy = y - 16 + k;
        yy = yy < 0 ? -yy : yy;            // reflect (no edge repeat)
        yy = yy > 223 ? 446 - yy : yy;
        acc += w * scores[(size_t)(b * 784 + (yy >> 3) * 28 + pw) * 9];
    }
    tH[idx] = acc / gsum;
}

__global__ void blur_w_kernel(const float* __restrict__ tH, float* __restrict__ out) {
    int idx = blockIdx.x * blockDim.x + threadIdx.x;
    if (idx >= 4 * 224 * 224) return;
    int x = idx % 224, y = (idx / 224) % 224, b = idx / (224 * 224);
    float acc = 0.f, gsum = 0.f;
    #pragma unroll
    for (int k = 0; k < 33; ++k) {
        float xk = (float)(k - 16);
        float w = expf(-xk * xk * (1.0f / 32.0f));
        gsum += w;
        int xx = x - 16 + k;
        xx = xx < 0 ? -xx : xx;
        xx = xx > 223 ? 446 - xx : xx;
        acc += w * tH[(b * 224 + y) * 28 + (xx >> 3)];
    }
    out[idx] = acc / gsum;
}

// ---------- anomaly score ----------
__global__ void score_kernel(const float* __restrict__ scores, float* __restrict__ out) {
    __shared__ float vmax[256];
    __shared__ int   vidx[256];
    int tid = threadIdx.x;
    float best = -3.4e38f; int bi = 0x7fffffff;
    for (int r = tid; r < N_ROWS; r += 256) {
        float v = scores[r * 9];
        if (v > best) { best = v; bi = r; }
    }
    vmax[tid] = best; vidx[tid] = bi;
    __syncthreads();
    for (int s = 128; s > 0; s >>= 1) {
        if (tid < s) {
            if (vmax[tid + s] > vmax[tid] ||
                (vmax[tid + s] == vmax[tid] && vidx[tid + s] < vidx[tid])) {
                vmax[tid] = vmax[tid + s]; vidx[tid] = vidx[tid + s];
            }
        }
        __syncthreads();
    }
    if (tid == 0) {
        int idx = vidx[0];
        float es = 0.f, em = -3.4e38f;
        #pragma unroll
        for (int s = 0; s < 9; ++s) {
            float e = expf(scores[idx * 9 + s]);
            es += e; em = fmaxf(em, e);
        }
        out[4 * 224 * 224] = (1.0f - em / es) * vmax[0];
    }
}

// ---------- launch ----------
extern "C" void kernel_launch(void* const* d_in, const int* in_sizes, int n_in,
                              void* d_out, int out_size, void* d_ws, size_t ws_size,
                              hipStream_t stream) {
    const float* emb = (const float*)d_in[0];   // [3136,1536]
    const float* mb  = (const float*)d_in[1];   // [20000,1536]
    float* out = (float*)d_out;                 // 200704 amap + 1 score
    char* ws = (char*)d_ws;

    unsigned short* mbb      = (unsigned short*)(ws);             // 61,440,000 B
    unsigned short* embb     = (unsigned short*)(ws + 61440000);  //  9,633,792 B
    float*          x2       = (float*)(ws + 71073792);           //     12,544 B
    float*          y2       = (float*)(ws + 71086336);           //     80,000 B
    float*          partials = (float*)(ws + 71166464);           // 17,724,672 B
    float*          scores   = (float*)(ws + 88891136);           //    112,896 B
    float*          tH       = (float*)(ws + 89004032);           //    100,352 B  (total ~85 MB)

    cvt_bf16_kernel<<<2048, 256, 0, stream>>>(mb,  mbb,  M_COLS * KDIM / 4);
    cvt_bf16_kernel<<<1024, 256, 0, stream>>>(emb, embb, N_ROWS * KDIM / 4);
    row_norms_kernel<<<(N_ROWS + 3) / 4, 256, 0, stream>>>(emb, x2, N_ROWS);
    row_norms_kernel<<<M_COLS / 4, 256, 0, stream>>>(mb, y2, M_COLS);
    dist_topk_kernel<<<dim3(NCT, NRT), 256, 0, stream>>>(embb, mbb, x2, y2, partials);
    merge_topk_kernel<<<(N_ROWS + 255) / 256, 256, 0, stream>>>(partials, scores);
    blur_h_kernel<<<(4 * 224 * 28 + 255) / 256, 256, 0, stream>>>(scores, tH);
    blur_w_kernel<<<(4 * 224 * 224 + 255) / 256, 256, 0, stream>>>(tH, out);
    score_kernel<<<1, 256, 0, stream>>>(scores, out);
}

// Round 2
// 390.922 us; speedup vs baseline: 2.2927x; 2.2927x over previous
//
#include <hip/hip_runtime.h>

// ---------- types ----------
typedef __attribute__((ext_vector_type(8))) short bf16x8;
typedef __attribute__((ext_vector_type(4))) float f32x4;
typedef __attribute__((ext_vector_type(4))) int   i32x4;

#define N_ROWS 3136
#define M_COLS 20000
#define KDIM   1536
#define NCT    157            // ceil(20000/128)
#define NRT    25             // ceil(3136/128)
#define PPR    (NCT*9)        // partial candidates per row = 1413

#define GLOAD_LDS16(g, l) __builtin_amdgcn_global_load_lds( \
    (const __attribute__((address_space(1))) unsigned int*)(g), \
    (__attribute__((address_space(3))) unsigned int*)(l), 16, 0, 0)

__device__ inline unsigned short f2bf(float f) {
    unsigned u = __float_as_uint(f);
    u += 0x7FFFu + ((u >> 16) & 1u);   // RNE
    return (unsigned short)(u >> 16);
}

// sorted ascending insert, drop old max; all indices static after unroll
__device__ inline void t9_insert(float (&t)[9], float v) {
    #pragma unroll
    for (int s = 8; s >= 1; --s)
        t[s] = (v <= t[s-1]) ? t[s-1] : fminf(t[s], v);
    t[0] = fminf(t[0], v);
}

// ---------- fused f32->bf16 conversion + row squared norms (wave per row) ----------
__global__ void cvt_norm_kernel(const float* __restrict__ src,
                                unsigned short* __restrict__ dst,
                                float* __restrict__ norms, int rows) {
    int lane = threadIdx.x & 63;
    int row = blockIdx.x * (blockDim.x >> 6) + (threadIdx.x >> 6);
    if (row >= rows) return;
    const float4* p = (const float4*)(src + (size_t)row * KDIM);
    ushort4* q = (ushort4*)(dst + (size_t)row * KDIM);
    float s = 0.f;
    #pragma unroll
    for (int i = 0; i < 6; ++i) {              // 384 float4 / 64 lanes
        float4 v = p[lane + i * 64];
        s += v.x*v.x + v.y*v.y + v.z*v.z + v.w*v.w;
        ushort4 o;
        o.x = f2bf(v.x); o.y = f2bf(v.y); o.z = f2bf(v.z); o.w = f2bf(v.w);
        q[lane + i * 64] = o;
    }
    #pragma unroll
    for (int off = 32; off > 0; off >>= 1) s += __shfl_down(s, off);
    if (lane == 0) norms[row] = s;
}

// ---------- fused distance GEMM + per-tile top-9 ----------
// 128x128 tile, K-step 32, 4 waves (2x2), 16x16x32 bf16 MFMA, 4x4 frags/wave.
// Staging via global_load_lds width=16 (m97 structure); epilogue LDS overlaid on stage LDS.
union SMem {
    struct { unsigned short As[128 * 32]; unsigned short Bs[128 * 32]; } stage; // 16 KB
    struct { float Ds[64 * 133]; float T9[3 * 64 * 13]; } epi;                  // 44 KB
};

__global__ __launch_bounds__(256, 3) void dist_topk_kernel(
    const unsigned short* __restrict__ Ag,   // [3136][1536] bf16
    const unsigned short* __restrict__ Bg,   // [20000][1536] bf16
    const float* __restrict__ x2, const float* __restrict__ y2,
    float* __restrict__ partials)
{
    __shared__ __align__(16) SMem sm;

    const int tid = threadIdx.x;
    const int ct = blockIdx.x, rt = blockIdx.y;
    const int rowBase = rt * 128, colBase = ct * 128;
    const int wave = tid >> 6, lane = tid & 63;

    // staging addresses: 2 x 16B chunks per thread for each of A,B
    const unsigned short* pa[2];
    const unsigned short* pb[2];
    int ldsoff[2];
    #pragma unroll
    for (int i = 0; i < 2; ++i) {
        int flat = i * 256 + tid;        // 0..511
        int r = flat >> 2;               // tile row 0..127
        int kk = (flat & 3) * 8;         // k offset 0,8,16,24
        int ar = rowBase + r; ar = ar < N_ROWS ? ar : N_ROWS - 1;   // clamp
        int bc = colBase + r; bc = bc < M_COLS ? bc : M_COLS - 1;
        pa[i] = Ag + (size_t)ar * KDIM + kk;
        pb[i] = Bg + (size_t)bc * KDIM + kk;
        ldsoff[i] = flat * 8;            // ushort elements; bytes = flat*16 (lane-linear)
    }

    const int l15 = lane & 15;
    const int kb = (lane >> 4) * 8;          // A/B fragment k-base
    const int g4 = (lane >> 4) * 4;          // C fragment row-base
    const int wr = (wave >> 1) * 64;
    const int wc = (wave & 1) * 64;

    f32x4 acc[4][4] = {};

    for (int kt = 0; kt < 48; ++kt) {
        const int koff = kt * 32;
        #pragma unroll
        for (int i = 0; i < 2; ++i) {
            GLOAD_LDS16(pa[i] + koff, sm.stage.As + ldsoff[i]);
            GLOAD_LDS16(pb[i] + koff, sm.stage.Bs + ldsoff[i]);
        }
        __syncthreads();                     // drains vmcnt(0) -> staged data visible
        bf16x8 af[4], bfr[4];
        #pragma unroll
        for (int mi = 0; mi < 4; ++mi)
            af[mi] = *(const bf16x8*)(sm.stage.As + (wr + mi * 16 + l15) * 32 + kb);
        #pragma unroll
        for (int ni = 0; ni < 4; ++ni)
            bfr[ni] = *(const bf16x8*)(sm.stage.Bs + (wc + ni * 16 + l15) * 32 + kb);
        #pragma unroll
        for (int mi = 0; mi < 4; ++mi)
            #pragma unroll
            for (int ni = 0; ni < 4; ++ni)
                acc[mi][ni] = __builtin_amdgcn_mfma_f32_16x16x32_bf16(af[mi], bfr[ni], acc[mi][ni], 0, 0, 0);
        __syncthreads();                     // compute done before next overwrite
    }

    // epilogue: two passes of 64 rows (Ds/T9 overlay the stage LDS; safe after last barrier)
    for (int pass = 0; pass < 2; ++pass) {
        if ((wave >> 1) == pass) {
            #pragma unroll
            for (int ni = 0; ni < 4; ++ni) {
                int c = wc + ni * 16 + l15;
                int gc = colBase + c;
                float yv = y2[gc < M_COLS ? gc : M_COLS - 1];
                #pragma unroll
                for (int mi = 0; mi < 4; ++mi) {
                    #pragma unroll
                    for (int j = 0; j < 4; ++j) {
                        int rloc = mi * 16 + g4 + j;          // 0..63
                        int gr = rowBase + pass * 64 + rloc;
                        float xv = x2[gr < N_ROWS ? gr : N_ROWS - 1];
                        sm.epi.Ds[rloc * 133 + c] = xv + yv - 2.0f * acc[mi][ni][j];
                    }
                }
            }
        }
        __syncthreads();
        // 4-way column-split scan: thread (q, r) scans cols [q*32, q*32+32)
        int r = tid & 63, q = tid >> 6;
        int grow = rowBase + pass * 64 + r;
        int ncols = M_COLS - colBase; ncols = ncols < 128 ? ncols : 128;
        float t9[9];
        #pragma unroll
        for (int s = 0; s < 9; ++s) t9[s] = 3.4e38f;
        int cs = q * 32;
        int ce = (cs + 32 < ncols) ? cs + 32 : ncols;
        for (int c = cs; c < ce; ++c) t9_insert(t9, sm.epi.Ds[r * 133 + c]);
        if (q > 0) {
            #pragma unroll
            for (int s = 0; s < 9; ++s) sm.epi.T9[((q - 1) * 64 + r) * 13 + s] = t9[s];
        }
        __syncthreads();
        if (q == 0 && grow < N_ROWS) {
            #pragma unroll
            for (int qq = 0; qq < 3; ++qq)
                #pragma unroll
                for (int s = 0; s < 9; ++s)
                    t9_insert(t9, sm.epi.T9[(qq * 64 + r) * 13 + s]);
            float* dst = partials + (size_t)grow * PPR + ct * 9;
            #pragma unroll
            for (int s = 0; s < 9; ++s) dst[s] = t9[s];
        }
        __syncthreads();
    }
}

// ---------- merge 157 sorted-9 lists per row -> final top-9 (one WAVE per row) ----------
__global__ void merge_topk_kernel(const float* __restrict__ partials,
                                  float* __restrict__ scores) {
    int lane = threadIdx.x & 63;
    int row = blockIdx.x * 4 + (threadIdx.x >> 6);   // 4 waves/block, 784 blocks
    const float* p = partials + (size_t)row * PPR;
    float t9[9];
    #pragma unroll
    for (int s = 0; s < 9; ++s) t9[s] = 3.4e38f;
    for (int i = lane; i < PPR; i += 64) {           // coalesced strided scan
        float v = p[i];
        if (v < t9[8]) t9_insert(t9, v);
    }
    // butterfly merge of sorted-9 lists across 64 lanes
    #pragma unroll
    for (int off = 32; off > 0; off >>= 1) {
        float o[9];
        #pragma unroll
        for (int s = 0; s < 9; ++s) o[s] = __shfl_xor(t9[s], off);
        #pragma unroll
        for (int s = 0; s < 9; ++s)
            if (o[s] < t9[8]) t9_insert(t9, o[s]);
    }
    if (lane == 0) {
        #pragma unroll
        for (int s = 0; s < 9; ++s)
            scores[row * 9 + s] = sqrtf(fmaxf(t9[s], 0.f));
    }
}

// ---------- gaussian blur (fused with x8 nearest upsample), sigma=4, K=33 ----------
__global__ void blur_h_kernel(const float* __restrict__ scores, float* __restrict__ tH) {
    int idx = blockIdx.x * blockDim.x + threadIdx.x;
    if (idx >= 4 * 224 * 28) return;
    int pw = idx % 28, y = (idx / 28) % 224, b = idx / (28 * 224);
    float acc = 0.f, gsum = 0.f;
    #pragma unroll
    for (int k = 0; k < 33; ++k) {
        float xk = (float)(k - 16);
        float w = expf(-xk * xk * (1.0f / 32.0f));
        gsum += w;
        int yy = y - 16 + k;
        yy = yy < 0 ? -yy : yy;            // reflect (no edge repeat)
        yy = yy > 223 ? 446 - yy : yy;
        acc += w * scores[(size_t)(b * 784 + (yy >> 3) * 28 + pw) * 9];
    }
    tH[idx] = acc / gsum;
}

__global__ void blur_w_kernel(const float* __restrict__ tH, float* __restrict__ out) {
    int idx = blockIdx.x * blockDim.x + threadIdx.x;
    if (idx >= 4 * 224 * 224) return;
    int x = idx % 224, y = (idx / 224) % 224, b = idx / (224 * 224);
    float acc = 0.f, gsum = 0.f;
    #pragma unroll
    for (int k = 0; k < 33; ++k) {
        float xk = (float)(k - 16);
        float w = expf(-xk * xk * (1.0f / 32.0f));
        gsum += w;
        int xx = x - 16 + k;
        xx = xx < 0 ? -xx : xx;
        xx = xx > 223 ? 446 - xx : xx;
        acc += w * tH[(b * 224 + y) * 28 + (xx >> 3)];
    }
    out[idx] = acc / gsum;
}

// ---------- anomaly score ----------
__global__ void score_kernel(const float* __restrict__ scores, float* __restrict__ out) {
    __shared__ float vmax[256];
    __shared__ int   vidx[256];
    int tid = threadIdx.x;
    float best = -3.4e38f; int bi = 0x7fffffff;
    for (int r = tid; r < N_ROWS; r += 256) {
        float v = scores[r * 9];
        if (v > best) { best = v; bi = r; }
    }
    vmax[tid] = best; vidx[tid] = bi;
    __syncthreads();
    for (int s = 128; s > 0; s >>= 1) {
        if (tid < s) {
            if (vmax[tid + s] > vmax[tid] ||
                (vmax[tid + s] == vmax[tid] && vidx[tid + s] < vidx[tid])) {
                vmax[tid] = vmax[tid + s]; vidx[tid] = vidx[tid + s];
            }
        }
        __syncthreads();
    }
    if (tid == 0) {
        int idx = vidx[0];
        float es = 0.f, em = -3.4e38f;
        #pragma unroll
        for (int s = 0; s < 9; ++s) {
            float e = expf(scores[idx * 9 + s]);
            es += e; em = fmaxf(em, e);
        }
        out[4 * 224 * 224] = (1.0f - em / es) * vmax[0];
    }
}

// ---------- launch ----------
extern "C" void kernel_launch(void* const* d_in, const int* in_sizes, int n_in,
                              void* d_out, int out_size, void* d_ws, size_t ws_size,
                              hipStream_t stream) {
    const float* emb = (const float*)d_in[0];   // [3136,1536]
    const float* mb  = (const float*)d_in[1];   // [20000,1536]
    float* out = (float*)d_out;                 // 200704 amap + 1 score
    char* ws = (char*)d_ws;

    unsigned short* mbb      = (unsigned short*)(ws);             // 61,440,000 B
    unsigned short* embb     = (unsigned short*)(ws + 61440000);  //  9,633,792 B
    float*          x2       = (float*)(ws + 71073792);           //     12,544 B
    float*          y2       = (float*)(ws + 71086336);           //     80,000 B
    float*          partials = (float*)(ws + 71166464);           // 17,724,672 B
    float*          scores   = (float*)(ws + 88891136);           //    112,896 B
    float*          tH       = (float*)(ws + 89004032);           //    100,352 B  (total ~85 MB)

    cvt_norm_kernel<<<M_COLS / 4, 256, 0, stream>>>(mb, mbb, y2, M_COLS);
    cvt_norm_kernel<<<N_ROWS / 4, 256, 0, stream>>>(emb, embb, x2, N_ROWS);
    dist_topk_kernel<<<dim3(NCT, NRT), 256, 0, stream>>>(embb, mbb, x2, y2, partials);
    merge_topk_kernel<<<N_ROWS / 4, 256, 0, stream>>>(partials, scores);
    blur_h_kernel<<<(4 * 224 * 28 + 255) / 256, 256, 0, stream>>>(scores, tH);
    blur_w_kernel<<<(4 * 224 * 224 + 255) / 256, 256, 0, stream>>>(tH, out);
    score_kernel<<<1, 256, 0, stream>>>(scores, out);
}